// Round 1
// baseline (34.737 us; speedup 1.0000x reference)
//
#include <hip/hip_runtime.h>

// VectorQuantizer (per-dimension scalar codebooks), B=2048, D=128, K=512.
// Output: d_out[0] = loss (mean (q-z)^2), d_out[1..1+B*D) = quantized_st [B,D].
//
// Strategy: one block per (d, b-tile). d is block-uniform -> codebook row loads
// are scalar (s_load_dwordx16), consumed as SGPR operands by the VALU scan.
// Each thread owns one (b,d), scans all K=512 codes tracking (best_dist, best_code)
// with strict < (first-occurrence argmin, matching np.argmin), distance computed
// as (z-c)*(z-c) in fp32 exactly like the reference to stay bit-identical.

#define B_N 2048
#define D_N 128
#define K_N 512

__global__ __launch_bounds__(256) void vq_argmin_kernel(
    const float* __restrict__ z,
    const float* __restrict__ cb,
    float* __restrict__ out) {
    const int d = blockIdx.x & (D_N - 1);       // 128 dims
    const int btile = blockIdx.x >> 7;          // 8 batch tiles of 256
    const int b = (btile << 8) + threadIdx.x;

    const float zv = z[b * D_N + d];
    const float* __restrict__ crow = cb + d * K_N;  // wave-uniform pointer

    float best = 3.402823466e+38f;
    float bq = 0.0f;

    for (int k0 = 0; k0 < K_N; k0 += 16) {
        float c[16];
        #pragma unroll
        for (int j = 0; j < 16; ++j) c[j] = crow[k0 + j];  // uniform -> s_load
        #pragma unroll
        for (int j = 0; j < 16; ++j) {
            float diff = zv - c[j];      // same op order as reference
            float dd = diff * diff;
            bool lt = dd < best;         // strict <: keep FIRST min (np.argmin)
            best = lt ? dd : best;
            bq = lt ? c[j] : bq;
        }
    }

    // straight-through output, same fp order as reference: z + (q - z)
    out[1 + b * D_N + d] = zv + (bq - zv);

    // loss partial: (quantized - z)^2
    float err = bq - zv;
    float p = err * err;
    #pragma unroll
    for (int off = 32; off > 0; off >>= 1) p += __shfl_down(p, off, 64);

    __shared__ float wsum[4];
    const int lane = threadIdx.x & 63;
    const int wid = threadIdx.x >> 6;
    if (lane == 0) wsum[wid] = p;
    __syncthreads();
    if (threadIdx.x == 0) {
        float s = (wsum[0] + wsum[1]) + (wsum[2] + wsum[3]);
        atomicAdd(out, s * (1.0f / (B_N * D_N)));
    }
}

extern "C" void kernel_launch(void* const* d_in, const int* in_sizes, int n_in,
                              void* d_out, int out_size, void* d_ws, size_t ws_size,
                              hipStream_t stream) {
    const float* z  = (const float*)d_in[0];
    const float* cb = (const float*)d_in[1];
    float* out = (float*)d_out;

    // zero the loss accumulator each call (replay-deterministic)
    hipMemsetAsync(d_out, 0, sizeof(float), stream);

    const int blocks = (B_N / 256) * D_N;  // 8 * 128 = 1024
    vq_argmin_kernel<<<blocks, 256, 0, stream>>>(z, cb, out);
}

// Round 2
// 16.507 us; speedup vs baseline: 2.1044x; 2.1044x over previous
//
#include <hip/hip_runtime.h>

// VectorQuantizer (per-dim scalar codebooks), B=2048, D=128, K=512.
// out[0] = mean (q-z)^2 ; out[1..] = z + (q - z)  [B,D] row-major.
//
// R2 design:
//  - block-uniform d -> codebook row loads are scalar (s_load), SGPR operands.
//  - inner loop is 3 VALU ops per code: v_sub_f32, v_alignbit_b32 (rotl1),
//    v_min_u32. Key = (|diff|_bits<<1)|sign orders exactly by |diff| == order
//    of (z-c)^2 up to <=1-ulp equidistance (sub-threshold by construction).
//  - K-loop fully unrolled so scalar loads pipeline across the whole body.
//  - loss via per-block partials in d_ws + tiny reduce kernel (no atomics,
//    no memset node).

#define B_N 2048
#define D_N 128
#define K_N 512
#define NBLK ((B_N / 256) * D_N)  // 1024

__device__ __forceinline__ unsigned rotl1(unsigned x) { return (x << 1) | (x >> 31); }

__global__ __launch_bounds__(256) void vq_scan_kernel(
    const float* __restrict__ z,
    const float* __restrict__ cbk,
    float* __restrict__ out,
    float* __restrict__ partial) {
    const int d = blockIdx.x & (D_N - 1);
    const int btile = blockIdx.x >> 7;
    const int b = (btile << 8) + threadIdx.x;

    const float zv = z[b * D_N + d];
    const float* __restrict__ crow = cbk + d * K_N;  // wave-uniform -> s_load

    unsigned best0 = 0xFFFFFFFFu, best1 = 0xFFFFFFFFu;
    unsigned best2 = 0xFFFFFFFFu, best3 = 0xFFFFFFFFu;

    #pragma unroll
    for (int k0 = 0; k0 < K_N; k0 += 4) {
        // compile-time offsets -> compiler batches/hoists s_load_dwordx{4,8,16}
        float c0 = crow[k0 + 0], c1 = crow[k0 + 1];
        float c2 = crow[k0 + 2], c3 = crow[k0 + 3];
        float f0 = c0 - zv, f1 = c1 - zv, f2 = c2 - zv, f3 = c3 - zv;
        best0 = min(best0, rotl1(__float_as_uint(f0)));
        best1 = min(best1, rotl1(__float_as_uint(f1)));
        best2 = min(best2, rotl1(__float_as_uint(f2)));
        best3 = min(best3, rotl1(__float_as_uint(f3)));
    }

    unsigned best = min(min(best0, best1), min(best2, best3));
    float diff = __uint_as_float((best >> 1) | (best << 31));  // fl(q - z)

    out[1 + b * D_N + d] = zv + diff;  // same fp order as reference ST output

    // loss partial: (q - z)^2
    float p = diff * diff;
    #pragma unroll
    for (int off = 32; off > 0; off >>= 1) p += __shfl_down(p, off, 64);

    __shared__ float wsum[4];
    const int lane = threadIdx.x & 63;
    const int wid = threadIdx.x >> 6;
    if (lane == 0) wsum[wid] = p;
    __syncthreads();
    if (threadIdx.x == 0)
        partial[blockIdx.x] = (wsum[0] + wsum[1]) + (wsum[2] + wsum[3]);
}

__global__ __launch_bounds__(256) void vq_reduce_kernel(
    const float* __restrict__ partial, float* __restrict__ out) {
    // NBLK = 1024 partials, 256 threads x 4 each
    float p = 0.0f;
    #pragma unroll
    for (int j = 0; j < 4; ++j) p += partial[threadIdx.x + 256 * j];
    #pragma unroll
    for (int off = 32; off > 0; off >>= 1) p += __shfl_down(p, off, 64);

    __shared__ float wsum[4];
    const int lane = threadIdx.x & 63;
    const int wid = threadIdx.x >> 6;
    if (lane == 0) wsum[wid] = p;
    __syncthreads();
    if (threadIdx.x == 0) {
        float s = (wsum[0] + wsum[1]) + (wsum[2] + wsum[3]);
        out[0] = s * (1.0f / (B_N * D_N));
    }
}

extern "C" void kernel_launch(void* const* d_in, const int* in_sizes, int n_in,
                              void* d_out, int out_size, void* d_ws, size_t ws_size,
                              hipStream_t stream) {
    const float* z  = (const float*)d_in[0];
    const float* cb = (const float*)d_in[1];
    float* out = (float*)d_out;
    float* partial = (float*)d_ws;  // NBLK floats, fully overwritten each call

    vq_scan_kernel<<<NBLK, 256, 0, stream>>>(z, cb, out, partial);
    vq_reduce_kernel<<<1, 256, 0, stream>>>(partial, out);
}

// Round 3
// 16.152 us; speedup vs baseline: 2.1506x; 1.0219x over previous
//
#include <hip/hip_runtime.h>

// VectorQuantizer (per-dim scalar codebooks), B=2048, D=128, K=512.
// out[0] = mean (q-z)^2 ; out[1..] = z + (q - z)  [B,D] row-major.
//
// R3: inner loop restructured to 2.5 VALU ops/code:
//   per 4 codes: 4x v_sub_f32 (SGPR codebook operand), 4x v_alignbit_b32
//   (rotl1 key = (|diff|<<1)|sign, orders by |diff| == order of (z-c)^2),
//   2x v_min3_u32 (min(min(k,k),acc) pattern-matched by LLVM).
// Two independent accumulators halve the min-chain dependence depth.
// Reduce kernel and all summation orders identical to the passing R2.

#define B_N 2048
#define D_N 128
#define K_N 512
#define NBLK ((B_N / 256) * D_N)  // 1024

__device__ __forceinline__ unsigned rotl1(unsigned x) { return (x << 1) | (x >> 31); }
__device__ __forceinline__ unsigned umin3(unsigned a, unsigned b, unsigned c) {
    return min(min(a, b), c);  // -> v_min3_u32
}

__global__ __launch_bounds__(256) void vq_scan_kernel(
    const float* __restrict__ z,
    const float* __restrict__ cbk,
    float* __restrict__ out,
    float* __restrict__ partial) {
    const int d = blockIdx.x & (D_N - 1);
    const int btile = blockIdx.x >> 7;
    const int b = (btile << 8) + threadIdx.x;

    const float zv = z[b * D_N + d];
    const float* __restrict__ crow = cbk + d * K_N;  // wave-uniform -> s_load

    unsigned bestA = 0xFFFFFFFFu, bestB = 0xFFFFFFFFu;

    #pragma unroll
    for (int k0 = 0; k0 < K_N; k0 += 4) {
        float c0 = crow[k0 + 0], c1 = crow[k0 + 1];
        float c2 = crow[k0 + 2], c3 = crow[k0 + 3];
        unsigned q0 = rotl1(__float_as_uint(c0 - zv));
        unsigned q1 = rotl1(__float_as_uint(c1 - zv));
        unsigned q2 = rotl1(__float_as_uint(c2 - zv));
        unsigned q3 = rotl1(__float_as_uint(c3 - zv));
        bestA = umin3(q0, q1, bestA);
        bestB = umin3(q2, q3, bestB);
    }

    unsigned best = min(bestA, bestB);
    float diff = __uint_as_float((best >> 1) | (best << 31));  // fl(q - z)

    out[1 + b * D_N + d] = zv + diff;  // same fp order as reference ST output

    // loss partial: (q - z)^2  (identical structure to R2)
    float p = diff * diff;
    #pragma unroll
    for (int off = 32; off > 0; off >>= 1) p += __shfl_down(p, off, 64);

    __shared__ float wsum[4];
    const int lane = threadIdx.x & 63;
    const int wid = threadIdx.x >> 6;
    if (lane == 0) wsum[wid] = p;
    __syncthreads();
    if (threadIdx.x == 0)
        partial[blockIdx.x] = (wsum[0] + wsum[1]) + (wsum[2] + wsum[3]);
}

__global__ __launch_bounds__(256) void vq_reduce_kernel(
    const float* __restrict__ partial, float* __restrict__ out) {
    float p = 0.0f;
    #pragma unroll
    for (int j = 0; j < 4; ++j) p += partial[threadIdx.x + 256 * j];
    #pragma unroll
    for (int off = 32; off > 0; off >>= 1) p += __shfl_down(p, off, 64);

    __shared__ float wsum[4];
    const int lane = threadIdx.x & 63;
    const int wid = threadIdx.x >> 6;
    if (lane == 0) wsum[wid] = p;
    __syncthreads();
    if (threadIdx.x == 0) {
        float s = (wsum[0] + wsum[1]) + (wsum[2] + wsum[3]);
        out[0] = s * (1.0f / (B_N * D_N));
    }
}

extern "C" void kernel_launch(void* const* d_in, const int* in_sizes, int n_in,
                              void* d_out, int out_size, void* d_ws, size_t ws_size,
                              hipStream_t stream) {
    const float* z  = (const float*)d_in[0];
    const float* cb = (const float*)d_in[1];
    float* out = (float*)d_out;
    float* partial = (float*)d_ws;  // NBLK floats, fully overwritten each call

    vq_scan_kernel<<<NBLK, 256, 0, stream>>>(z, cb, out, partial);
    vq_reduce_kernel<<<1, 256, 0, stream>>>(partial, out);
}